// Round 10
// baseline (181.121 us; speedup 1.0000x reference)
//
#include <hip/hip_runtime.h>

// N=4, C=32(n_feats), H=W=300, P=5 fixed by setup_inputs.
#define HW        90000
#define OUT_HALF  11520000
#define CPLANE    11520000ull            // shorts per conv plane (4*90000*32)
#define WPACK_OFF  46080000ull           // bytes: 2 planes * 23.04 MB
#define WS_NEED    (46080000ull + 147456ull)

typedef short short8 __attribute__((ext_vector_type(8)));
typedef float f32x4  __attribute__((ext_vector_type(4)));

__device__ inline short f2bf(float f) {
    unsigned u = __builtin_bit_cast(unsigned, f);
    u += 0x7fff + ((u >> 16) & 1);            // RNE
    return (short)(u >> 16);
}
__device__ inline float bf2f(short s) {
    unsigned u = ((unsigned)(unsigned short)s) << 16;
    return __builtin_bit_cast(float, u);
}

// ---- weight pack for mfma_f32_16x16x32_bf16 A-operand, gamma folded in ----
// A-frag: lane l holds A[row=l&15][k = 8*(l>>4)+e], e=0..7 contiguous.
// layout: [conv][kb=4][t=9][h=2][lane=64][e=8], co = h*16+(l&15), cin = kb*32+8*(l>>4)+e
__global__ __launch_bounds__(256)
void pack_weights(const float* __restrict__ wR, const float* __restrict__ wH,
                  const float* __restrict__ rg, const float* __restrict__ hg,
                  short* __restrict__ wpack) {
    int id = blockIdx.x * 256 + threadIdx.x;   // 2*4*9*2*64*8 = 73728
    if (id >= 73728) return;
    int e    = id & 7;
    int lane = (id >> 3) & 63;
    int h    = (id >> 9) & 1;
    int t    = (id >> 10) % 9;
    int kb   = ((id >> 10) / 9) & 3;
    int conv = id / 36864;
    int co   = h * 16 + (lane & 15);
    int cin  = kb * 32 + (lane >> 4) * 8 + e;
    const float* w = conv ? wH : wR;
    const float* g = conv ? hg : rg;
    wpack[id] = f2bf(w[(co * 128 + cin) * 9 + t] * g[cin >> 5]);
}

// ---- NCHW f32 -> per-conv NHWC bf16 planes: cmb[conv][n][y][x][32ch] ----
__global__ __launch_bounds__(256)
void nchw2nhwc(const float* __restrict__ xrgb, const float* __restrict__ yhsi,
               short* __restrict__ cmb) {
    int wave = threadIdx.x >> 6, lane = threadIdx.x & 63;
    if (lane >= 60) return;
    int y = blockIdx.y * 4 + wave;
    int x = blockIdx.x * 60 + lane;
    int n = blockIdx.z;
    const float* xb = xrgb + n * 32 * HW + y * 300 + x;
    const float* yb = yhsi + n * 32 * HW + y * 300 + x;
    size_t pxo = ((size_t)n * HW + y * 300 + x) * 32;
    short* d0 = cmb + pxo;
    short* d1 = cmb + CPLANE + pxo;
    #pragma unroll
    for (int q = 0; q < 4; ++q) {
        short8 v0, v1;
        #pragma unroll
        for (int e = 0; e < 8; ++e) {
            int c = q * 8 + e;
            v0[e] = f2bf((c < 16) ? xb[(16 + c) * HW] : yb[c * HW]);
            v1[e] = f2bf((c < 16) ? xb[c * HW] : yb[(c - 16) * HW]);
        }
        *(short8*)(d0 + q * 8) = v0;
        *(short8*)(d1 + q * 8) = v1;
    }
}

// ---- conv: 12x16 tile, halo 14x18=252px, dbuf 31.5KB LDS, T14 async staging ----
__global__ __launch_bounds__(256, 5)
void conv_mfma(const short* __restrict__ cmb_all, const short* __restrict__ wpack,
               const int* __restrict__ corr,
               const float* __restrict__ bR, const float* __restrict__ bH,
               float* __restrict__ out) {
    __shared__ alignas(16) char lds[2][16128];   // 2 x 252px x 64B
    int tile = blockIdx.x;
    int n = blockIdx.y;
    int conv = blockIdx.z;
    int ty = tile / 19, tx = tile - ty * 19;
    int y0 = ty * 12, x0 = tx * 16;
    int tid = threadIdx.x;

    const short* cmb = cmb_all + conv * CPLANE + (size_t)n * HW * 32;
    const short* wp  = wpack + conv * 36864;

    // stager setup: thread tid<252 owns halo pixel tid; prefetch corr + all soffs
    bool stager = tid < 252;
    bool svalid = false;
    int soffs[4] = {0, 0, 0, 0};
    if (stager) {
        int hr = tid / 18, hc = tid - hr * 18;
        int gy = y0 + hr - 1, gx = x0 + hc - 1;
        svalid = (gy >= 0 && gy < 300 && gx >= 0 && gx < 300);
        if (svalid) {
            int pr = gy / 5, pc = gx / 5;
            int sj = pr * 60 + pc;
            int sintra = (gy - pr * 5) * 300 + (gx - pc * 5);
            const int* scr = corr + (n * 3600 + sj) * 4;
            int j1 = scr[1], j2 = scr[2], j3 = scr[3];
            soffs[0] = (sj / 60) * 1500 + (sj % 60) * 5 + sintra;
            soffs[1] = (j1 / 60) * 1500 + (j1 % 60) * 5 + sintra;
            soffs[2] = (j2 / 60) * 1500 + (j2 % 60) * 5 + sintra;
            soffs[3] = (j3 / 60) * 1500 + (j3 % 60) * 5 + sintra;
        }
    }
    int swz = (tid & 7) << 4;
    int b0  = tid * 64;

    short8 sv0 = {0,0,0,0,0,0,0,0}, sv1 = sv0, sv2 = sv0, sv3 = sv0;

    // STAGE_LOAD(k): issue 4 global loads into sv0..sv3 (no LDS write -> no drain)
    #define STAGE_LOAD(k)                                                        \
        do {                                                                     \
            if (svalid) {                                                        \
                const short8* s = (const short8*)(cmb + (size_t)soffs[(k)] * 32);\
                sv0 = s[0]; sv1 = s[1]; sv2 = s[2]; sv3 = s[3];                  \
            } else { sv0 = sv1 = sv2 = sv3 = (short8){0,0,0,0,0,0,0,0}; }        \
        } while (0)
    // STAGE_WRITE(buf): swizzled ds_writes of the in-flight registers
    #define STAGE_WRITE(buf)                                                     \
        do {                                                                     \
            char* d = lds[(buf)];                                                \
            *(short8*)(d + ((b0 +  0) ^ swz)) = sv0;                             \
            *(short8*)(d + ((b0 + 16) ^ swz)) = sv1;                             \
            *(short8*)(d + ((b0 + 32) ^ swz)) = sv2;                             \
            *(short8*)(d + ((b0 + 48) ^ swz)) = sv3;                             \
        } while (0)

    if (stager) { STAGE_LOAD(0); STAGE_WRITE(0); }
    __syncthreads();

    int wave = tid >> 6, lane = tid & 63;
    int l15 = lane & 15, lh = lane >> 4;

    f32x4 acc[3][2];
    #pragma unroll
    for (int g = 0; g < 3; ++g)
        #pragma unroll
        for (int h = 0; h < 2; ++h)
            acc[g][h] = (f32x4){0.f, 0.f, 0.f, 0.f};

    #pragma unroll
    for (int kb = 0; kb < 4; ++kb) {
        if (kb < 3 && stager) STAGE_LOAD(kb + 1);      // issue early (T14)
        const char* base = lds[kb & 1];
        #pragma unroll
        for (int t = 0; t < 9; ++t) {
            int dy = t / 3 - 1, dx = t % 3 - 1;
            short8 a0 = *(const short8*)(wp + (((kb * 9 + t) * 2 + 0) * 64 + lane) * 8);
            short8 a1 = *(const short8*)(wp + (((kb * 9 + t) * 2 + 1) * 64 + lane) * 8);
            #pragma unroll
            for (int g = 0; g < 3; ++g) {
                int hp = (wave * 3 + g + dy + 1) * 18 + (l15 + dx + 1);
                short8 b = *(const short8*)(base + ((hp * 64 + lh * 16) ^ ((hp & 7) << 4)));
                acc[g][0] = __builtin_amdgcn_mfma_f32_16x16x32_bf16(a0, b, acc[g][0], 0, 0, 0);
                acc[g][1] = __builtin_amdgcn_mfma_f32_16x16x32_bf16(a1, b, acc[g][1], 0, 0, 0);
            }
        }
        if (kb < 3) {
            if (stager) STAGE_WRITE((kb + 1) & 1);     // write late, after compute
            __syncthreads();
        }
    }

    // epilogue: residual+bias from cmb (dense 64B per lane, bf16)
    const float* bias = conv ? bH : bR;
    #pragma unroll
    for (int g = 0; g < 3; ++g) {
        int gy = y0 + wave * 3 + g;          // always < 300 (25*12=300)
        int gx = x0 + l15;
        if (gx < 300) {
            int pixo = gy * 300 + gx;
            const short* resp = cmb + (size_t)pixo * 32;
            short8 r0 = *(const short8*)(resp);
            short8 r1 = *(const short8*)(resp + 8);
            short8 r2 = *(const short8*)(resp + 16);
            short8 r3 = *(const short8*)(resp + 24);
            #pragma unroll
            for (int h = 0; h < 2; ++h) {
                #pragma unroll
                for (int reg = 0; reg < 4; ++reg) {
                    int co = h * 16 + lh * 4 + reg;
                    int q = co >> 3, e = co & 7;
                    float res = bf2f(q == 0 ? r0[e] : q == 1 ? r1[e] : q == 2 ? r2[e] : r3[e]);
                    out[conv * OUT_HALF + (n * 32 + co) * HW + pixo] = acc[g][h][reg] + bias[co] + res;
                }
            }
        }
    }
    #undef STAGE_LOAD
    #undef STAGE_WRITE
}

// ---- fallback (round-1 kernel) if ws too small ----
__global__ __launch_bounds__(256)
void fused_gather_conv(const float* __restrict__ xrgb, const float* __restrict__ yhsi,
                       const int* __restrict__ corr, const float* __restrict__ rgb_gamma,
                       const float* __restrict__ hsi_gamma, const float* __restrict__ wR,
                       const float* __restrict__ bR, const float* __restrict__ wH,
                       const float* __restrict__ bH, float* __restrict__ out) {
    int tid = blockIdx.x * blockDim.x + threadIdx.x;
    if (tid >= 4 * HW) return;
    int n = tid / HW, pix = tid - n * HW;
    int y = pix / 300, x = pix - y * 300;
    const int* idx = corr + n * (3600 * 4);
    const float* xb = xrgb + n * (32 * HW);
    const float* yb = yhsi + n * (32 * HW);
    float accR[32], accH[32];
    #pragma unroll
    for (int i = 0; i < 32; ++i) { accR[i] = 0.f; accH[i] = 0.f; }
    for (int k = 0; k < 4; ++k) {
        float gr = rgb_gamma[k], gh = hsi_gamma[k];
        int off[9];
        #pragma unroll
        for (int t = 0; t < 9; ++t) {
            int dy = t / 3 - 1, dx = t % 3 - 1;
            int yy = y + dy, xx = x + dx;
            int o = -1;
            if (yy >= 0 && yy < 300 && xx >= 0 && xx < 300) {
                int pr = yy / 5, pc = xx / 5;
                int j = pr * 60 + pc;
                int jp = (k == 0) ? j : idx[j * 4 + k];
                o = ((jp / 60) * 5 + (yy - pr * 5)) * 300 + (jp % 60) * 5 + (xx - pc * 5);
            }
            off[t] = o;
        }
        for (int c = 0; c < 32; ++c) {
            const float* srcR = (c < 16) ? (xb + (16 + c) * HW) : (yb + c * HW);
            const float* srcH = (c < 16) ? (xb + c * HW) : (yb + (c - 16) * HW);
            float vr[9], vh[9];
            #pragma unroll
            for (int t = 0; t < 9; ++t) {
                bool vld = off[t] >= 0;
                vr[t] = vld ? gr * srcR[off[t]] : 0.f;
                vh[t] = vld ? gh * srcH[off[t]] : 0.f;
            }
            const float* wRp = wR + (k * 32 + c) * 9;
            const float* wHp = wH + (k * 32 + c) * 9;
            #pragma unroll
            for (int t = 0; t < 9; ++t)
                #pragma unroll
                for (int co = 0; co < 32; ++co) {
                    accR[co] = fmaf(vr[t], wRp[co * 1152 + t], accR[co]);
                    accH[co] = fmaf(vh[t], wHp[co * 1152 + t], accH[co]);
                }
        }
    }
    #pragma unroll
    for (int co = 0; co < 32; ++co) {
        float resR = (co < 16) ? xb[(16 + co) * HW + pix] : yb[co * HW + pix];
        float resH = (co < 16) ? xb[co * HW + pix] : yb[(co - 16) * HW + pix];
        out[(n * 32 + co) * HW + pix]            = accR[co] + bR[co] + resR;
        out[OUT_HALF + (n * 32 + co) * HW + pix] = accH[co] + bH[co] + resH;
    }
}

extern "C" void kernel_launch(void* const* d_in, const int* in_sizes, int n_in,
                              void* d_out, int out_size, void* d_ws, size_t ws_size,
                              hipStream_t stream) {
    const float* xrgb = (const float*)d_in[0];
    const float* yhsi = (const float*)d_in[1];
    const int*   corr = (const int*)d_in[2];
    const float* rg   = (const float*)d_in[3];
    const float* hg   = (const float*)d_in[4];
    const float* wR   = (const float*)d_in[5];
    const float* bR   = (const float*)d_in[6];
    const float* wH   = (const float*)d_in[7];
    const float* bH   = (const float*)d_in[8];
    float* out = (float*)d_out;

    if (ws_size >= WS_NEED) {
        short* cmb   = (short*)d_ws;
        short* wpack = (short*)((char*)d_ws + WPACK_OFF);
        hipLaunchKernelGGL(pack_weights, dim3(288), dim3(256), 0, stream, wR, wH, rg, hg, wpack);
        hipLaunchKernelGGL(nchw2nhwc, dim3(5, 75, 4), dim3(256), 0, stream, xrgb, yhsi, cmb);
        hipLaunchKernelGGL(conv_mfma, dim3(475, 4, 2), dim3(256), 0, stream,
                           cmb, wpack, corr, bR, bH, out);
    } else {
        int total = 4 * HW;
        hipLaunchKernelGGL(fused_gather_conv, dim3((total + 255) / 256), dim3(256), 0, stream,
                           xrgb, yhsi, corr, rg, hg, wR, bR, wH, bH, out);
    }
}

// Round 11
// 137.809 us; speedup vs baseline: 1.3143x; 1.3143x over previous
//
#include <hip/hip_runtime.h>

// N=4, C=32(n_feats), H=W=300, P=5 fixed by setup_inputs.
#define HW        90000
#define OUT_HALF  11520000
#define CPLANE    11520000ull            // shorts per conv plane (4*90000*32)
#define WPACK_OFF  46080000ull           // bytes: 2 planes * 23.04 MB
#define WS_NEED    (46080000ull + 147456ull)

typedef short short8 __attribute__((ext_vector_type(8)));
typedef float f32x4  __attribute__((ext_vector_type(4)));

__device__ inline short f2bf(float f) {
    unsigned u = __builtin_bit_cast(unsigned, f);
    u += 0x7fff + ((u >> 16) & 1);            // RNE
    return (short)(u >> 16);
}
__device__ inline float bf2f(short s) {
    unsigned u = ((unsigned)(unsigned short)s) << 16;
    return __builtin_bit_cast(float, u);
}

// ---- weight pack for mfma_f32_16x16x32_bf16 A-operand, gamma folded in ----
// A-frag: lane l holds A[row=l&15][k = 8*(l>>4)+e], e=0..7 contiguous.
// layout: [conv][kb=4][t=9][h=2][lane=64][e=8], co = h*16+(l&15), cin = kb*32+8*(l>>4)+e
__global__ __launch_bounds__(256)
void pack_weights(const float* __restrict__ wR, const float* __restrict__ wH,
                  const float* __restrict__ rg, const float* __restrict__ hg,
                  short* __restrict__ wpack) {
    int id = blockIdx.x * 256 + threadIdx.x;   // 2*4*9*2*64*8 = 73728
    if (id >= 73728) return;
    int e    = id & 7;
    int lane = (id >> 3) & 63;
    int h    = (id >> 9) & 1;
    int t    = (id >> 10) % 9;
    int kb   = ((id >> 10) / 9) & 3;
    int conv = id / 36864;
    int co   = h * 16 + (lane & 15);
    int cin  = kb * 32 + (lane >> 4) * 8 + e;
    const float* w = conv ? wH : wR;
    const float* g = conv ? hg : rg;
    wpack[id] = f2bf(w[(co * 128 + cin) * 9 + t] * g[cin >> 5]);
}

// ---- NCHW f32 -> per-conv NHWC bf16 planes: cmb[conv][n][y][x][32ch] ----
__global__ __launch_bounds__(256)
void nchw2nhwc(const float* __restrict__ xrgb, const float* __restrict__ yhsi,
               short* __restrict__ cmb) {
    int wave = threadIdx.x >> 6, lane = threadIdx.x & 63;
    if (lane >= 60) return;
    int y = blockIdx.y * 4 + wave;
    int x = blockIdx.x * 60 + lane;
    int n = blockIdx.z;
    const float* xb = xrgb + n * 32 * HW + y * 300 + x;
    const float* yb = yhsi + n * 32 * HW + y * 300 + x;
    size_t pxo = ((size_t)n * HW + y * 300 + x) * 32;
    short* d0 = cmb + pxo;
    short* d1 = cmb + CPLANE + pxo;
    #pragma unroll
    for (int q = 0; q < 4; ++q) {
        short8 v0, v1;
        #pragma unroll
        for (int e = 0; e < 8; ++e) {
            int c = q * 8 + e;
            v0[e] = f2bf((c < 16) ? xb[(16 + c) * HW] : yb[c * HW]);
            v1[e] = f2bf((c < 16) ? xb[c * HW] : yb[(c - 16) * HW]);
        }
        *(short8*)(d0 + q * 8) = v0;
        *(short8*)(d1 + q * 8) = v1;
    }
}

// ---- conv: 16x16 tile, halo 18x18=324px, dbuf 41.5KB LDS, row-shared B-frags ----
__global__ __launch_bounds__(256, 3)
void conv_mfma(const short* __restrict__ cmb_all, const short* __restrict__ wpack,
               const int* __restrict__ corr,
               const float* __restrict__ bR, const float* __restrict__ bH,
               float* __restrict__ out) {
    __shared__ alignas(16) char lds[2][20736];   // 2 x 324px x 64B
    int tile = blockIdx.x;
    int n = blockIdx.y;
    int conv = blockIdx.z;
    int ty = tile / 19, tx = tile - ty * 19;
    int y0 = ty * 16, x0 = tx * 16;
    int tid = threadIdx.x;

    const short* cmb = cmb_all + conv * CPLANE + (size_t)n * HW * 32;
    const short* wp  = wpack + conv * 36864;

    // staging: pixel A = tid (always <324), pixel B = tid+256 (tid<68 only)
    int  pA = tid, pB = tid + 256;
    bool hasB = pB < 324;
    bool vA = false, vB = false;
    int sA0=0,sA1=0,sA2=0,sA3=0, sB0=0,sB1=0,sB2=0,sB3=0;
    {
        int hr = pA / 18, hc = pA - hr * 18;
        int gy = y0 + hr - 1, gx = x0 + hc - 1;
        vA = (gy >= 0 && gy < 300 && gx >= 0 && gx < 300);
        if (vA) {
            int pr = gy / 5, pc = gx / 5;
            int sj = pr * 60 + pc;
            int sintra = (gy - pr * 5) * 300 + (gx - pc * 5);
            const int* scr = corr + (n * 3600 + sj) * 4;
            int j1 = scr[1], j2 = scr[2], j3 = scr[3];
            sA0 = (sj / 60) * 1500 + (sj % 60) * 5 + sintra;
            sA1 = (j1 / 60) * 1500 + (j1 % 60) * 5 + sintra;
            sA2 = (j2 / 60) * 1500 + (j2 % 60) * 5 + sintra;
            sA3 = (j3 / 60) * 1500 + (j3 % 60) * 5 + sintra;
        }
    }
    if (hasB) {
        int hr = pB / 18, hc = pB - hr * 18;
        int gy = y0 + hr - 1, gx = x0 + hc - 1;
        vB = (gy >= 0 && gy < 300 && gx >= 0 && gx < 300);
        if (vB) {
            int pr = gy / 5, pc = gx / 5;
            int sj = pr * 60 + pc;
            int sintra = (gy - pr * 5) * 300 + (gx - pc * 5);
            const int* scr = corr + (n * 3600 + sj) * 4;
            int j1 = scr[1], j2 = scr[2], j3 = scr[3];
            sB0 = (sj / 60) * 1500 + (sj % 60) * 5 + sintra;
            sB1 = (j1 / 60) * 1500 + (j1 % 60) * 5 + sintra;
            sB2 = (j2 / 60) * 1500 + (j2 % 60) * 5 + sintra;
            sB3 = (j3 / 60) * 1500 + (j3 % 60) * 5 + sintra;
        }
    }

    #define STAGE1(buf, px, valid, soff)                                         \
        do {                                                                     \
            short8 v0 = {0,0,0,0,0,0,0,0}, v1 = v0, v2 = v0, v3 = v0;            \
            if (valid) {                                                         \
                const short8* s = (const short8*)(cmb + (size_t)(soff) * 32);    \
                v0 = s[0]; v1 = s[1]; v2 = s[2]; v3 = s[3];                      \
            }                                                                    \
            char* d = lds[(buf)];                                                \
            int b0 = (px) * 64, sz = ((px) & 7) << 4;                            \
            *(short8*)(d + ((b0 +  0) ^ sz)) = v0;                               \
            *(short8*)(d + ((b0 + 16) ^ sz)) = v1;                               \
            *(short8*)(d + ((b0 + 32) ^ sz)) = v2;                               \
            *(short8*)(d + ((b0 + 48) ^ sz)) = v3;                               \
        } while (0)
    #define STAGE(buf, k)                                                        \
        do {                                                                     \
            STAGE1(buf, pA, vA, sA##k);                                          \
            if (hasB) STAGE1(buf, pB, vB, sB##k);                                \
        } while (0)

    STAGE(0, 0);
    __syncthreads();

    int wave = tid >> 6, lane = tid & 63;
    int l15 = lane & 15, lh = lane >> 4;
    int wr = wave * 4;                       // wave's first output row within tile

    f32x4 acc[4][2];
    #pragma unroll
    for (int g = 0; g < 4; ++g)
        #pragma unroll
        for (int h = 0; h < 2; ++h)
            acc[g][h] = (f32x4){0.f, 0.f, 0.f, 0.f};

    #pragma unroll
    for (int kb = 0; kb < 4; ++kb) {
        if (kb == 0) STAGE(1, 1);
        if (kb == 1) STAGE(0, 2);
        if (kb == 2) STAGE(1, 3);
        const char* base = lds[kb & 1];
        #pragma unroll
        for (int dxi = 0; dxi < 3; ++dxi) {
            // A-frags for the 3 dy taps x 2 co-halves of this dx
            short8 a[3][2];
            #pragma unroll
            for (int dyi = 0; dyi < 3; ++dyi) {
                int t = dyi * 3 + dxi;
                a[dyi][0] = *(const short8*)(wp + (((kb * 9 + t) * 2 + 0) * 64 + lane) * 8);
                a[dyi][1] = *(const short8*)(wp + (((kb * 9 + t) * 2 + 1) * 64 + lane) * 8);
            }
            // B row-fragments: input rows wr-1 .. wr+4  (rr = g+dy+1 in 0..5)
            short8 b[6];
            #pragma unroll
            for (int rr = 0; rr < 6; ++rr) {
                int hp = (wr + rr) * 18 + (l15 + dxi);
                b[rr] = *(const short8*)(base + ((hp * 64 + lh * 16) ^ ((hp & 7) << 4)));
            }
            #pragma unroll
            for (int g = 0; g < 4; ++g) {
                #pragma unroll
                for (int dyi = 0; dyi < 3; ++dyi) {
                    acc[g][0] = __builtin_amdgcn_mfma_f32_16x16x32_bf16(a[dyi][0], b[g + dyi], acc[g][0], 0, 0, 0);
                    acc[g][1] = __builtin_amdgcn_mfma_f32_16x16x32_bf16(a[dyi][1], b[g + dyi], acc[g][1], 0, 0, 0);
                }
            }
        }
        if (kb < 3) __syncthreads();
    }

    // epilogue: residual+bias from cmb (dense 64B per lane, bf16)
    const float* bias = conv ? bH : bR;
    #pragma unroll
    for (int g = 0; g < 4; ++g) {
        int gy = y0 + wr + g;
        int gx = x0 + l15;
        if (gy < 300 && gx < 300) {
            int pixo = gy * 300 + gx;
            const short* resp = cmb + (size_t)pixo * 32;
            short8 r0 = *(const short8*)(resp);
            short8 r1 = *(const short8*)(resp + 8);
            short8 r2 = *(const short8*)(resp + 16);
            short8 r3 = *(const short8*)(resp + 24);
            #pragma unroll
            for (int h = 0; h < 2; ++h) {
                #pragma unroll
                for (int reg = 0; reg < 4; ++reg) {
                    int co = h * 16 + lh * 4 + reg;
                    int q = co >> 3, e = co & 7;
                    float res = bf2f(q == 0 ? r0[e] : q == 1 ? r1[e] : q == 2 ? r2[e] : r3[e]);
                    out[conv * OUT_HALF + (n * 32 + co) * HW + pixo] = acc[g][h][reg] + bias[co] + res;
                }
            }
        }
    }
    #undef STAGE
    #undef STAGE1
}

// ---- fallback (round-1 kernel) if ws too small ----
__global__ __launch_bounds__(256)
void fused_gather_conv(const float* __restrict__ xrgb, const float* __restrict__ yhsi,
                       const int* __restrict__ corr, const float* __restrict__ rgb_gamma,
                       const float* __restrict__ hsi_gamma, const float* __restrict__ wR,
                       const float* __restrict__ bR, const float* __restrict__ wH,
                       const float* __restrict__ bH, float* __restrict__ out) {
    int tid = blockIdx.x * blockDim.x + threadIdx.x;
    if (tid >= 4 * HW) return;
    int n = tid / HW, pix = tid - n * HW;
    int y = pix / 300, x = pix - y * 300;
    const int* idx = corr + n * (3600 * 4);
    const float* xb = xrgb + n * (32 * HW);
    const float* yb = yhsi + n * (32 * HW);
    float accR[32], accH[32];
    #pragma unroll
    for (int i = 0; i < 32; ++i) { accR[i] = 0.f; accH[i] = 0.f; }
    for (int k = 0; k < 4; ++k) {
        float gr = rgb_gamma[k], gh = hsi_gamma[k];
        int off[9];
        #pragma unroll
        for (int t = 0; t < 9; ++t) {
            int dy = t / 3 - 1, dx = t % 3 - 1;
            int yy = y + dy, xx = x + dx;
            int o = -1;
            if (yy >= 0 && yy < 300 && xx >= 0 && xx < 300) {
                int pr = yy / 5, pc = xx / 5;
                int j = pr * 60 + pc;
                int jp = (k == 0) ? j : idx[j * 4 + k];
                o = ((jp / 60) * 5 + (yy - pr * 5)) * 300 + (jp % 60) * 5 + (xx - pc * 5);
            }
            off[t] = o;
        }
        for (int c = 0; c < 32; ++c) {
            const float* srcR = (c < 16) ? (xb + (16 + c) * HW) : (yb + c * HW);
            const float* srcH = (c < 16) ? (xb + c * HW) : (yb + (c - 16) * HW);
            float vr[9], vh[9];
            #pragma unroll
            for (int t = 0; t < 9; ++t) {
                bool vld = off[t] >= 0;
                vr[t] = vld ? gr * srcR[off[t]] : 0.f;
                vh[t] = vld ? gh * srcH[off[t]] : 0.f;
            }
            const float* wRp = wR + (k * 32 + c) * 9;
            const float* wHp = wH + (k * 32 + c) * 9;
            #pragma unroll
            for (int t = 0; t < 9; ++t)
                #pragma unroll
                for (int co = 0; co < 32; ++co) {
                    accR[co] = fmaf(vr[t], wRp[co * 1152 + t], accR[co]);
                    accH[co] = fmaf(vh[t], wHp[co * 1152 + t], accH[co]);
                }
        }
    }
    #pragma unroll
    for (int co = 0; co < 32; ++co) {
        float resR = (co < 16) ? xb[(16 + co) * HW + pix] : yb[co * HW + pix];
        float resH = (co < 16) ? xb[co * HW + pix] : yb[(co - 16) * HW + pix];
        out[(n * 32 + co) * HW + pix]            = accR[co] + bR[co] + resR;
        out[OUT_HALF + (n * 32 + co) * HW + pix] = accH[co] + bH[co] + resH;
    }
}

extern "C" void kernel_launch(void* const* d_in, const int* in_sizes, int n_in,
                              void* d_out, int out_size, void* d_ws, size_t ws_size,
                              hipStream_t stream) {
    const float* xrgb = (const float*)d_in[0];
    const float* yhsi = (const float*)d_in[1];
    const int*   corr = (const int*)d_in[2];
    const float* rg   = (const float*)d_in[3];
    const float* hg   = (const float*)d_in[4];
    const float* wR   = (const float*)d_in[5];
    const float* bR   = (const float*)d_in[6];
    const float* wH   = (const float*)d_in[7];
    const float* bH   = (const float*)d_in[8];
    float* out = (float*)d_out;

    if (ws_size >= WS_NEED) {
        short* cmb   = (short*)d_ws;
        short* wpack = (short*)((char*)d_ws + WPACK_OFF);
        hipLaunchKernelGGL(pack_weights, dim3(288), dim3(256), 0, stream, wR, wH, rg, hg, wpack);
        hipLaunchKernelGGL(nchw2nhwc, dim3(5, 75, 4), dim3(256), 0, stream, xrgb, yhsi, cmb);
        hipLaunchKernelGGL(conv_mfma, dim3(361, 4, 2), dim3(256), 0, stream,
                           cmb, wpack, corr, bR, bH, out);
    } else {
        int total = 4 * HW;
        hipLaunchKernelGGL(fused_gather_conv, dim3((total + 255) / 256), dim3(256), 0, stream,
                           xrgb, yhsi, corr, rg, hg, wR, bR, wH, bH, out);
    }
}